// Round 4
// baseline (324.719 us; speedup 1.0000x reference)
//
#include <hip/hip_runtime.h>
#include <hip/hip_bf16.h>
#include <stdint.h>

#define EPS 1e-6f
#define N_EMB 65536
#define K_CENT 1024
#define DIM 512

typedef __attribute__((ext_vector_type(8))) short short8;
typedef __attribute__((ext_vector_type(4))) float f32x4;

// ---------------- ws layout v6 (bytes) ----------------
// [0)         ck_term 1024 f                     (ends 4096)
// [4096)      en_term 65536 f                    (ends 266240)
// [266240)    Pk      up-to-8*65536 u64 (4 slices used) (ends 4460544)
// [4460544)   E_bf16  65536*512 u16 = 64 MB      (ends 71569408)
// [71569408)  C_bf16  1024*512 u16 = 1 MB        (ends 72617984)
// [72617984)  gpart   32*3*1024 f = 384 KB       (ends 73011200)
// [73011200)  ticket  1 u32                      (ends 73011204)
#define WS6_BYTES 73011204ull

__device__ inline unsigned long long shflx64(unsigned long long v, int m) {
    int lo = __shfl_xor((int)(unsigned)(v & 0xffffffffull), m);
    int hi = __shfl_xor((int)(unsigned)(v >> 32), m);
    return ((unsigned long long)(unsigned)hi << 32) | (unsigned)lo;
}

__device__ inline unsigned pack_bf2(float x, float y) {
    __hip_bfloat162 h = __float22bfloat162_rn(make_float2(x, y));
    union { __hip_bfloat162 h; unsigned u; } c;
    c.h = h;
    return c.u;
}

__device__ inline uint4 pack_bf16x8(float4 a, float4 b) {
    uint4 r;
    r.x = pack_bf2(a.x, a.y);
    r.y = pack_bf2(a.z, a.w);
    r.z = pack_bf2(b.x, b.y);
    r.w = pack_bf2(b.z, b.w);
    return r;
}

// ---------------------------------------------------------------------------
// conv_v6: fp32->bf16 mirrors + row terms, 32 rows per block (8 per wave).
// ---------------------------------------------------------------------------
__global__ __launch_bounds__(256) void conv_v6_kernel(
    const float* __restrict__ E, const float* __restrict__ C,
    unsigned short* __restrict__ Eb, unsigned short* __restrict__ Cb,
    float* __restrict__ en_term, float* __restrict__ ck_term,
    unsigned int* __restrict__ ticket)
{
    const int wave = threadIdx.x >> 6;
    const int lane = threadIdx.x & 63;

    const float* X; unsigned short* Xb; float* term; float sa, c0; int row0;
    if (blockIdx.x < 32) {
        if (blockIdx.x == 0 && threadIdx.x == 0) *ticket = 0u;
        row0 = blockIdx.x * 32 + wave * 8;
        X = C; Xb = Cb; term = ck_term; sa = 2.0f * EPS; c0 = 0.0f;
    } else {
        row0 = (blockIdx.x - 32) * 32 + wave * 8;
        X = E; Xb = Eb; term = en_term; sa = -2.0f * EPS;
        c0 = (float)DIM * EPS * EPS;
    }

    #pragma unroll
    for (int r = 0; r < 8; r++) {
        const int row = row0 + r;
        const float* p = X + (size_t)row * DIM + lane * 8;
        float4 a = *(const float4*)(p);
        float4 b = *(const float4*)(p + 4);

        *(uint4*)&Xb[(size_t)row * DIM + lane * 8] = pack_bf16x8(a, b);

        float s  = a.x + a.y + a.z + a.w + b.x + b.y + b.z + b.w;
        float sq = a.x*a.x + a.y*a.y + a.z*a.z + a.w*a.w
                 + b.x*b.x + b.y*b.y + b.z*b.z + b.w*b.w;
        #pragma unroll
        for (int off = 32; off; off >>= 1) {
            s  += __shfl_down(s,  off);
            sq += __shfl_down(sq, off);
        }
        if (lane == 0) term[row] = sq + sa * s + c0;
    }
}

// ---------------------------------------------------------------------------
// mfma_assign_v9: m201-faithful phase shape. 256x256, 8 waves (2Mx4N), BK=64.
// Per phase: {ds_reads BEFORE barrier | 1 stage unit | counted vmcnt} ->
// s_barrier -> lgkmcnt(0)+sched_barrier(0) -> setprio(1) 16 MFMA setprio(0)
// -> s_barrier. Stage order per step t: A(t+1,0)@p0 B(t+1,0)@p1 B(t+1,1)@p2
// A(t+1,1)@p3; vmcnt(4)@p0,p1,p3 (peeled last step: vmcnt(2)@p0, (0)@p1).
// Each wait confirms the units needed ONE phase later; the following barrier
// publishes it collectively. B fragments held in regs (phase reads 12/4/8/0).
// Bit-identical keys to v6/v8 (same per-acc K order, same swizzle pair).
// Deadlock-free by construction: uniform control flow through all barriers.
// ---------------------------------------------------------------------------
#define BM 256
#define BN 256
#define BK 64
#define NK (DIM / BK)   // 8

__global__ __launch_bounds__(512, 2) void mfma_assign_v9_kernel(
    const unsigned short* __restrict__ Eb, const unsigned short* __restrict__ Cb,
    const float* __restrict__ ck_term, unsigned long long* __restrict__ Pk)
{
    // A: [2 buf][2 mq][2 wm][64 rows][64 elems] = 2 x 32 KB
    // B: [2 buf][2 nh][4 wn][32 rows][64 elems] = 2 x 32 KB
    __shared__ unsigned short As[2 * 16384];
    __shared__ unsigned short Bs[2 * 16384];
    __shared__ unsigned long long red[BM][4];

    const int tid  = threadIdx.x;
    const int lane = tid & 63;
    const int wave = tid >> 6;       // 0..7
    const int wm   = wave >> 2;      // 0..1
    const int wn   = wave & 3;       // 0..3
    const int quad = lane >> 4;      // 0..3
    const int col  = lane & 15;

    const unsigned bid = blockIdx.x;
    const unsigned wg  = (bid & 7u) * 128u + (bid >> 3);   // XCD swizzle (1024%8==0)
    const int et = (int)(wg >> 2);
    const int ct = (int)(wg & 3);
    const int erow0 = et * BM;
    const int k0    = ct * BN;

    // ---- staging decomposition (verified v8): unit row u, pre-swizzled src,
    // linear dest. Hoisted global base pointers per (mq|nh, j).
    int du_[2];
    const unsigned short* sA[2][2];  // [mq][j]
    const unsigned short* sB[2][2];  // [nh][j]
    #pragma unroll
    for (int j = 0; j < 2; j++) {
        const int u  = (wave * 2 + j) * 8 + (lane >> 3);     // 0..127
        const int sg = ((lane & 7) ^ (u & 7)) * 8;           // src elem offset
        du_[j] = (wave * 2 + j) * 512 + lane * 8;            // dest elems in unit
        #pragma unroll
        for (int mq = 0; mq < 2; mq++)
            sA[mq][j] = Eb + (size_t)(erow0 + (u >> 6) * 128 + mq * 64 + (u & 63)) * DIM + sg;
        #pragma unroll
        for (int nh = 0; nh < 2; nh++)
            sB[nh][j] = Cb + (size_t)(k0 + (u >> 5) * 64 + nh * 32 + (u & 31)) * DIM + sg;
    }

    auto stageA = [&](int kt, int mq) {
        unsigned short* dst = As + (kt & 1) * 16384 + mq * 8192;
        #pragma unroll
        for (int j = 0; j < 2; j++)
            __builtin_amdgcn_global_load_lds(
                (const __attribute__((address_space(1))) void*)(sA[mq][j] + kt * BK),
                (__attribute__((address_space(3))) void*)(dst + du_[j]), 16, 0, 0);
    };
    auto stageB = [&](int kt, int nh) {
        unsigned short* dst = Bs + (kt & 1) * 16384 + nh * 8192;
        #pragma unroll
        for (int j = 0; j < 2; j++)
            __builtin_amdgcn_global_load_lds(
                (const __attribute__((address_space(1))) void*)(sB[nh][j] + kt * BK),
                (__attribute__((address_space(3))) void*)(dst + du_[j]), 16, 0, 0);
    };

    // ---- hoisted LDS read offsets (swizzled, loop-invariant)
    int offA[4][2];
    #pragma unroll
    for (int a = 0; a < 4; a++)
        #pragma unroll
        for (int ks = 0; ks < 2; ks++)
            offA[a][ks] = (a * 16 + col) * 64 + (((ks * 4 + quad) ^ (col & 7)) * 8);

    f32x4 acc[8][4];
    #pragma unroll
    for (int mi = 0; mi < 8; mi++)
        #pragma unroll
        for (int ni = 0; ni < 4; ni++)
            acc[mi][ni] = (f32x4){0.f, 0.f, 0.f, 0.f};

    short8 afr[4][2], bfr0[2][2], bfr1[2][2];

    auto LDA = [&](const unsigned short* base) {   // base = As+buf+mq*8192+wm*4096
        #pragma unroll
        for (int a = 0; a < 4; a++)
            #pragma unroll
            for (int ks = 0; ks < 2; ks++)
                afr[a][ks] = *(const short8*)(base + offA[a][ks]);
    };
    auto LDB = [&](short8 (*bf)[2], const unsigned short* base) { // Bs+buf+nh*8192+wn*2048
        #pragma unroll
        for (int b = 0; b < 2; b++)
            #pragma unroll
            for (int ks = 0; ks < 2; ks++)
                bf[b][ks] = *(const short8*)(base + offA[b][ks]);
    };
    auto MM = [&](int mq, int nh, short8 (*bf)[2]) {
        __builtin_amdgcn_s_setprio(1);
        #pragma unroll
        for (int a = 0; a < 4; a++)
            #pragma unroll
            for (int b = 0; b < 2; b++) {
                const int mi = mq * 4 + a;
                const int ni = nh * 2 + b;
                acc[mi][ni] = __builtin_amdgcn_mfma_f32_16x16x32_bf16(
                    afr[a][0], bf[b][0], acc[mi][ni], 0, 0, 0);
                acc[mi][ni] = __builtin_amdgcn_mfma_f32_16x16x32_bf16(
                    afr[a][1], bf[b][1], acc[mi][ni], 0, 0, 0);
            }
        __builtin_amdgcn_s_setprio(0);
    };

    #define FENCE()  asm volatile("" ::: "memory")
    #define VMCNT(n) asm volatile("s_waitcnt vmcnt(" #n ")" ::: "memory")
    #define LGKM0()  do { asm volatile("s_waitcnt lgkmcnt(0)" ::: "memory"); \
                          __builtin_amdgcn_sched_barrier(0); } while (0)

    // ---- prologue: step-0 units in ledger order A0,B0,B1,A1
    stageA(0, 0); stageB(0, 0);
    FENCE();                       // keep {A0,B0} as the oldest-4 set
    stageB(0, 1); stageA(0, 1);
    VMCNT(4);                      // A(0,0)+B(0,0) landed
    __builtin_amdgcn_s_barrier();

    for (int t = 0; t < NK - 1; t++) {
        const unsigned short* Ab = As + (t & 1) * 16384;
        const unsigned short* Bb = Bs + (t & 1) * 16384;

        // phase 0: reads A(t,0)+B(t,0); stage A(t+1,0); confirm B(t,1)
        LDA(Ab + wm * 4096);
        LDB(bfr0, Bb + wn * 2048);
        stageA(t + 1, 0);
        VMCNT(4);
        __builtin_amdgcn_s_barrier();
        LGKM0();
        MM(0, 0, bfr0);
        __builtin_amdgcn_s_barrier();

        // phase 1: reads B(t,1); stage B(t+1,0); confirm A(t,1)
        LDB(bfr1, Bb + 8192 + wn * 2048);
        stageB(t + 1, 0);
        VMCNT(4);
        __builtin_amdgcn_s_barrier();
        LGKM0();
        MM(0, 1, bfr1);
        __builtin_amdgcn_s_barrier();

        // phase 2: reads A(t,1); stage B(t+1,1); no wait needed
        LDA(Ab + 8192 + wm * 4096);
        stageB(t + 1, 1);
        __builtin_amdgcn_s_barrier();
        LGKM0();
        MM(1, 1, bfr1);
        __builtin_amdgcn_s_barrier();

        // phase 3: no reads; stage A(t+1,1); confirm A(t+1,0)+B(t+1,0)
        stageA(t + 1, 1);
        VMCNT(4);
        __builtin_amdgcn_s_barrier();
        MM(1, 0, bfr0);
        __builtin_amdgcn_s_barrier();
    }

    // ---- peeled last step (t = NK-1, buf = 1): no staging, drain
    {
        const unsigned short* Ab = As + ((NK - 1) & 1) * 16384;
        const unsigned short* Bb = Bs + ((NK - 1) & 1) * 16384;

        LDA(Ab + wm * 4096);
        LDB(bfr0, Bb + wn * 2048);
        VMCNT(2);                  // confirm B(t,1)
        __builtin_amdgcn_s_barrier();
        LGKM0();
        MM(0, 0, bfr0);
        __builtin_amdgcn_s_barrier();

        LDB(bfr1, Bb + 8192 + wn * 2048);
        VMCNT(0);                  // confirm A(t,1)
        __builtin_amdgcn_s_barrier();
        LGKM0();
        MM(0, 1, bfr1);
        __builtin_amdgcn_s_barrier();

        LDA(Ab + 8192 + wm * 4096);
        __builtin_amdgcn_s_barrier();
        LGKM0();
        MM(1, 1, bfr1);
        MM(1, 0, bfr0);
    }
    __builtin_amdgcn_sched_barrier(0);

    // ---- argmin epilogue (identical key math to verified v6/v8) ----
    float ck[4];
    #pragma unroll
    for (int ni = 0; ni < 4; ni++)
        ck[ni] = ck_term[k0 + wn * 64 + ni * 16 + col];

    #pragma unroll
    for (int mi = 0; mi < 8; mi++) {
        #pragma unroll
        for (int r = 0; r < 4; r++) {
            unsigned long long key = ~0ull;
            #pragma unroll
            for (int ni = 0; ni < 4; ni++) {
                float metric = fmaf(-2.0f, acc[mi][ni][r], ck[ni]);
                unsigned mb = __float_as_uint(metric);
                mb = (mb & 0x80000000u) ? ~mb : (mb | 0x80000000u);
                unsigned idx = (unsigned)(k0 + wn * 64 + ni * 16 + col);
                unsigned long long kk = ((unsigned long long)mb << 10) | idx;
                if (kk < key) key = kk;
            }
            #pragma unroll
            for (int s = 1; s < 16; s <<= 1) {
                unsigned long long o = shflx64(key, s);
                if (o < key) key = o;
            }
            if (col == 0) red[wm * 128 + mi * 16 + quad * 4 + r][wn] = key;
        }
    }
    __syncthreads();

    if (tid < BM) {
        unsigned long long a = red[tid][0];
        unsigned long long b = red[tid][1];
        unsigned long long c = red[tid][2];
        unsigned long long d = red[tid][3];
        unsigned long long m0 = a < b ? a : b;
        unsigned long long m1 = c < d ? c : d;
        Pk[(size_t)ct * N_EMB + erow0 + tid] = m0 < m1 ? m0 : m1;
    }
    #undef FENCE
    #undef VMCNT
    #undef LGKM0
}

// ---------------------------------------------------------------------------
// reduce_finalize: 32 blocks. Merge 4 Pk slices per emb, finish distance,
// per-block LDS partials, last-block election reduces 32 partials -> 3 outs.
// ---------------------------------------------------------------------------
#define RED_BLOCKS 32
__global__ __launch_bounds__(256) void reduce_finalize_v6_kernel(
    const unsigned long long* __restrict__ Pk, const float* __restrict__ en_term,
    float* __restrict__ gpart, unsigned int* __restrict__ ticket,
    float* __restrict__ out)
{
    __shared__ float cnt_s[K_CENT];
    __shared__ float sum_s[K_CENT];
    __shared__ unsigned max_s[K_CENT];

    const int tid = threadIdx.x;
    for (int k = tid; k < K_CENT; k += 256) {
        cnt_s[k] = 0.f; sum_s[k] = 0.f; max_s[k] = 0u;
    }
    __syncthreads();

    for (int i = blockIdx.x * 256 + tid; i < N_EMB; i += RED_BLOCKS * 256) {
        unsigned long long k = Pk[i];
        #pragma unroll
        for (int ct = 1; ct < 4; ct++) {
            unsigned long long o = Pk[(size_t)ct * N_EMB + i];
            if (o < k) k = o;
        }
        unsigned mb = (unsigned)(k >> 10);
        int idx = (int)(k & 1023u);
        unsigned b = (mb & 0x80000000u) ? (mb ^ 0x80000000u) : ~mb;
        float metric = __uint_as_float(b);
        float sq = metric + en_term[i];
        float dist = sqrtf(fmaxf(sq, 0.f));
        atomicAdd(&cnt_s[idx], 1.0f);
        atomicAdd(&sum_s[idx], dist);
        atomicMax(&max_s[idx], __float_as_uint(dist));
    }
    __syncthreads();

    float* gp = gpart + (size_t)blockIdx.x * 3 * K_CENT;
    for (int k = tid; k < K_CENT; k += 256) {
        __hip_atomic_store(&gp[k], cnt_s[k],
                           __ATOMIC_RELAXED, __HIP_MEMORY_SCOPE_AGENT);
        __hip_atomic_store(&gp[K_CENT + k], sum_s[k],
                           __ATOMIC_RELAXED, __HIP_MEMORY_SCOPE_AGENT);
        __hip_atomic_store(&gp[2 * K_CENT + k], __uint_as_float(max_s[k]),
                           __ATOMIC_RELAXED, __HIP_MEMORY_SCOPE_AGENT);
    }
    __threadfence();
    __syncthreads();

    __shared__ int lastf;
    if (tid == 0)
        lastf = (atomicAdd(ticket, 1u) == (unsigned)(RED_BLOCKS - 1));
    __syncthreads();
    if (!lastf) return;

    float a = 0.f, m = 0.f, c = 0.f;
    for (int k = tid; k < K_CENT; k += 256) {
        float cc = 0.f, ss = 0.f;
        unsigned mx = 0u;
        #pragma unroll 4
        for (int bb = 0; bb < RED_BLOCKS; bb++) {
            const float* gq = gpart + (size_t)bb * 3 * K_CENT;
            cc += __hip_atomic_load(&gq[k], __ATOMIC_RELAXED,
                                    __HIP_MEMORY_SCOPE_AGENT);
            ss += __hip_atomic_load(&gq[K_CENT + k], __ATOMIC_RELAXED,
                                    __HIP_MEMORY_SCOPE_AGENT);
            float mv = __hip_atomic_load(&gq[2 * K_CENT + k], __ATOMIC_RELAXED,
                                         __HIP_MEMORY_SCOPE_AGENT);
            unsigned mu = __float_as_uint(mv);
            if (mu > mx) mx = mu;
        }
        a += ss / (cc + 1.0f);
        m += __uint_as_float(mx);
        c += cc;
    }
    __shared__ float sa[4], sm[4], sc[4];
    #pragma unroll
    for (int off = 32; off; off >>= 1) {
        a += __shfl_down(a, off);
        m += __shfl_down(m, off);
        c += __shfl_down(c, off);
    }
    const int lane = tid & 63, w = tid >> 6;
    if (lane == 0) { sa[w] = a; sm[w] = m; sc[w] = c; }
    __syncthreads();
    if (tid == 0) {
        a = sa[0] + sa[1] + sa[2] + sa[3];
        m = sm[0] + sm[1] + sm[2] + sm[3];
        c = sc[0] + sc[1] + sc[2] + sc[3];
        out[0] = a / (float)K_CENT;
        out[1] = m / (float)K_CENT;
        out[2] = c / (float)K_CENT;
    }
}

// ---------------------------------------------------------------------------
// fp32 fallback path (round-1) if ws is too small.
// ---------------------------------------------------------------------------
__global__ __launch_bounds__(256) void row_stats_kernel(
    const float* __restrict__ X, float* __restrict__ term,
    float sa, float c0)
{
    const int wave = threadIdx.x >> 6;
    const int lane = threadIdx.x & 63;
    const int row  = blockIdx.x * 4 + wave;
    const float* p = X + (size_t)row * DIM;
    float4 a = *(const float4*)&p[lane * 4];
    float4 b = *(const float4*)&p[256 + lane * 4];
    float s  = a.x + a.y + a.z + a.w + b.x + b.y + b.z + b.w;
    float sq = a.x*a.x + a.y*a.y + a.z*a.z + a.w*a.w
             + b.x*b.x + b.y*b.y + b.z*b.z + b.w*b.w;
    #pragma unroll
    for (int off = 32; off; off >>= 1) {
        s  += __shfl_down(s,  off);
        sq += __shfl_down(sq, off);
    }
    if (lane == 0) term[row] = sq + sa * s + c0;
}

__global__ __launch_bounds__(256) void assign_kernel(
    const float* __restrict__ E, const float* __restrict__ C,
    const float* __restrict__ ck_term, const float* __restrict__ en_term,
    float* __restrict__ counts, float* __restrict__ sums,
    unsigned int* __restrict__ maxs)
{
    __shared__ float Es[16][64];
    __shared__ float Cs[16][64];
    __shared__ float red_sq[16][64];
    __shared__ int   red_idx[16][64];

    const int tid     = threadIdx.x;
    const int n0      = blockIdx.x * 64;
    const int en_base = (tid & 15) * 4;
    const int ck_base = (tid >> 4) * 4;
    const int tc      = tid >> 4;
    const int l_row = tid >> 2;
    const int l_col = (tid & 3) * 4;

    float et[4];
    #pragma unroll
    for (int i = 0; i < 4; i++) et[i] = en_term[n0 + en_base + i];
    float best[4];
    int   bidx[4];
    #pragma unroll
    for (int i = 0; i < 4; i++) { best[i] = 3.4e38f; bidx[i] = 0; }

    for (int kt = 0; kt < K_CENT; kt += 64) {
        float acc[4][4];
        #pragma unroll
        for (int i = 0; i < 4; i++)
            #pragma unroll
            for (int j = 0; j < 4; j++) acc[i][j] = 0.f;
        for (int dt = 0; dt < DIM; dt += 16) {
            __syncthreads();
            float4 ev = *(const float4*)&E[(size_t)(n0 + l_row) * DIM + dt + l_col];
            float4 cv = *(const float4*)&C[(size_t)(kt + l_row) * DIM + dt + l_col];
            Es[l_col + 0][l_row] = ev.x; Es[l_col + 1][l_row] = ev.y;
            Es[l_col + 2][l_row] = ev.z; Es[l_col + 3][l_row] = ev.w;
            Cs[l_col + 0][l_row] = cv.x; Cs[l_col + 1][l_row] = cv.y;
            Cs[l_col + 2][l_row] = cv.z; Cs[l_col + 3][l_row] = cv.w;
            __syncthreads();
            #pragma unroll
            for (int dd = 0; dd < 16; dd++) {
                float4 e4 = *(const float4*)&Es[dd][en_base];
                float4 c4 = *(const float4*)&Cs[dd][ck_base];
                float ee[4] = { e4.x, e4.y, e4.z, e4.w };
                float cc[4] = { c4.x, c4.y, c4.z, c4.w };
                #pragma unroll
                for (int i = 0; i < 4; i++)
                    #pragma unroll
                    for (int j = 0; j < 4; j++)
                        acc[i][j] = fmaf(ee[i], cc[j], acc[i][j]);
            }
        }
        #pragma unroll
        for (int j = 0; j < 4; j++) {
            float ckt = ck_term[kt + ck_base + j];
            int   kg  = kt + ck_base + j;
            #pragma unroll
            for (int i = 0; i < 4; i++) {
                float sqv = ckt + et[i] - 2.0f * acc[i][j];
                if (sqv < best[i]) { best[i] = sqv; bidx[i] = kg; }
            }
        }
    }
    #pragma unroll
    for (int i = 0; i < 4; i++) {
        red_sq[tc][en_base + i]  = best[i];
        red_idx[tc][en_base + i] = bidx[i];
    }
    __syncthreads();
    if (tid < 64) {
        float b  = red_sq[0][tid];
        int   bi = red_idx[0][tid];
        #pragma unroll
        for (int t = 1; t < 16; t++) {
            float v  = red_sq[t][tid];
            int   vi = red_idx[t][tid];
            if (v < b || (v == b && vi < bi)) { b = v; bi = vi; }
        }
        float dist = sqrtf(fmaxf(b, 0.f));
        atomicAdd(&counts[bi], 1.0f);
        atomicAdd(&sums[bi], dist);
        atomicMax(&maxs[bi], __float_as_uint(dist));
    }
}

__global__ __launch_bounds__(1024) void finalize_kernel(
    const float* __restrict__ counts, const float* __restrict__ sums,
    const float* __restrict__ maxs, float* __restrict__ out)
{
    const int k = threadIdx.x;
    float c = counts[k];
    float s = sums[k];
    float m = maxs[k];
    float a = s / (c + 1.0f);
    __shared__ float sa[16], sm[16], sc[16];
    #pragma unroll
    for (int off = 32; off; off >>= 1) {
        a += __shfl_down(a, off);
        m += __shfl_down(m, off);
        c += __shfl_down(c, off);
    }
    const int lane = k & 63, w = k >> 6;
    if (lane == 0) { sa[w] = a; sm[w] = m; sc[w] = c; }
    __syncthreads();
    if (k < 64) {
        a = (k < 16) ? sa[k] : 0.f;
        m = (k < 16) ? sm[k] : 0.f;
        c = (k < 16) ? sc[k] : 0.f;
        #pragma unroll
        for (int off = 8; off; off >>= 1) {
            a += __shfl_down(a, off);
            m += __shfl_down(m, off);
            c += __shfl_down(c, off);
        }
        if (k == 0) {
            out[0] = a / (float)K_CENT;
            out[1] = m / (float)K_CENT;
            out[2] = c / (float)K_CENT;
        }
    }
}

extern "C" void kernel_launch(void* const* d_in, const int* in_sizes, int n_in,
                              void* d_out, int out_size, void* d_ws, size_t ws_size,
                              hipStream_t stream) {
    const float* E = (const float*)d_in[0];   // (65536, 512)
    const float* C = (const float*)d_in[1];   // (1024, 512)

    char* wsb = (char*)d_ws;

    if (ws_size >= WS6_BYTES) {
        float* ck_term         = (float*)(wsb + 0);
        float* en_term         = (float*)(wsb + 4096);
        unsigned long long* Pk = (unsigned long long*)(wsb + 266240);
        unsigned short* Eb     = (unsigned short*)(wsb + 4460544);
        unsigned short* Cb     = (unsigned short*)(wsb + 71569408);
        float* gpart           = (float*)(wsb + 72617984);
        unsigned int* ticket   = (unsigned int*)(wsb + 73011200);

        conv_v6_kernel<<<32 + N_EMB / 32, 256, 0, stream>>>(
            E, C, Eb, Cb, en_term, ck_term, ticket);
        mfma_assign_v9_kernel<<<(N_EMB / BM) * (K_CENT / BN), 512, 0, stream>>>(
            Eb, Cb, ck_term, Pk);
        reduce_finalize_v6_kernel<<<RED_BLOCKS, 256, 0, stream>>>(
            Pk, en_term, gpart, ticket, (float*)d_out);
    } else {
        float* counts  = (float*)(wsb + 0);
        float* sums    = (float*)(wsb + 4096);
        float* maxs    = (float*)(wsb + 8192);
        float* ck_term = (float*)(wsb + 12288);
        float* en_term = (float*)(wsb + 16384);
        hipMemsetAsync(counts, 0, 3 * K_CENT * sizeof(float), stream);
        row_stats_kernel<<<K_CENT / 4, 256, 0, stream>>>(
            C, ck_term, 2.0f * EPS, 0.0f);
        row_stats_kernel<<<N_EMB / 4, 256, 0, stream>>>(
            E, en_term, -2.0f * EPS, (float)DIM * EPS * EPS);
        assign_kernel<<<N_EMB / 64, 256, 0, stream>>>(
            E, C, ck_term, en_term, counts, sums, (unsigned int*)maxs);
        finalize_kernel<<<1, 1024, 0, stream>>>(counts, sums, maxs, (float*)d_out);
    }
}